// Round 4
// baseline (1852.943 us; speedup 1.0000x reference)
//
#include <hip/hip_runtime.h>
#include <hip/hip_bf16.h>

// Problem constants (fixed shapes from the reference)
#define M_ROWS 25088   // 8 * 3136 embedding rows
#define N_CENT 4096    // centroids
#define K_DIM  1536    // feature dim (elements == bytes in fp8)
#define TILE   128
#define BK     128     // fp8 elements (=bytes) per K-chunk

typedef __attribute__((ext_vector_type(8))) int   int8v;    // f8f6f4 A/B frag (32 fp8)
typedef __attribute__((ext_vector_type(4))) int   int4v;
typedef __attribute__((ext_vector_type(4))) float floatx4;  // MFMA accumulator

typedef __attribute__((address_space(1))) const void gvoid;
typedef __attribute__((address_space(3))) void lvoid;

__device__ __forceinline__ void load_lds16(const void* g, void* l) {
    // async global->LDS, 16B per lane; LDS dest = wave-uniform base + lane*16
    __builtin_amdgcn_global_load_lds((gvoid*)g, (lvoid*)l, 16, 0, 0);
}

// Wave-per-row convert: fp32 -> fp8 e4m3 (OCP, HW cvt) + fp32 sum-of-squares.
// Block = 256 threads = 4 waves = 4 rows; 6 float4 loads/lane; shuffle-only
// reduction. Norms stay exact fp32 so only the dot term carries fp8 noise.
__global__ __launch_bounds__(256) void convert_rows(
    const float* __restrict__ src, unsigned int* __restrict__ dst,
    float* __restrict__ norms, unsigned int* __restrict__ minbuf, int nrows)
{
    const int row  = blockIdx.x * 4 + (threadIdx.x >> 6);
    const int lane = threadIdx.x & 63;
    if (row >= nrows) return;

    const float4* s = (const float4*)(src + (size_t)row * K_DIM);
    unsigned int* d = dst + (size_t)row * (K_DIM / 4);

    float4 v[6];
    #pragma unroll
    for (int j = 0; j < 6; ++j) v[j] = s[lane + j * 64];   // 6 loads in flight

    float ssq = 0.f;
    #pragma unroll
    for (int j = 0; j < 6; ++j) {
        ssq += v[j].x * v[j].x + v[j].y * v[j].y + v[j].z * v[j].z + v[j].w * v[j].w;
        int u = __builtin_amdgcn_cvt_pk_fp8_f32(v[j].x, v[j].y, 0, false);
        u     = __builtin_amdgcn_cvt_pk_fp8_f32(v[j].z, v[j].w, u, true);
        d[lane + j * 64] = (unsigned int)u;
    }

    #pragma unroll
    for (int off = 32; off >= 1; off >>= 1) ssq += __shfl_down(ssq, off, 64);
    if (lane == 0) {
        norms[row] = ssq;
        if (minbuf) minbuf[row] = 0x7F800000u;  // +inf bits (ws re-poisoned each launch)
    }
}

// 128x128 MX-fp8 MFMA GEMM tile (16x16x128 f8f6f4, unit E8M0 scales) with
// fused per-row min(dist^2) epilogue. A = embeds [M,K] fp8, B = centroids
// [N,K] fp8 (NT layout).
//
// LDS layout is rotation-swizzled: row R stores its 8 16B-chunks at slot
// (chunk + R) & 7. Row stride is 128 B = exactly 32 banks, so unswizzled
// frag reads (16 rows @ fixed column) would be 16-phase b128 (2x the 8-phase
// floor); the rotation spreads the 64 lanes over all 32 banks (8-phase
// floor). The swizzle is applied on the GLOBAL source address so that
// global_load_lds's fixed lane->base+l*16 LDS mapping produces it, and each
// 8-lane group still covers one full contiguous 128-B global row (coalesced).
__global__ __launch_bounds__(256, 3) void gemm_min(
    const unsigned char* __restrict__ A,
    const unsigned char* __restrict__ B,
    const float* __restrict__ nx,
    const float* __restrict__ nc,
    unsigned int* __restrict__ minbuf)
{
    __shared__ unsigned char sA[TILE * BK];   // 16 KB
    __shared__ unsigned char sB[TILE * BK];   // 16 KB

    const int tid  = threadIdx.x;
    const int wave = tid >> 6;
    const int lane = tid & 63;
    const int quad = lane >> 4;
    const int l15  = lane & 15;
    const int tile_n = blockIdx.x * TILE;
    const int tile_m = blockIdx.y * TILE;

    // Staging: one load = 64 lanes x 16 B = 8 rows x 128 B. Round r (0..3),
    // wave w -> LDS rows (r*4+w)*8..+8 (bytes (r*4+w)*1024). Lane l -> row
    // l>>3 within the group; global chunk = ((l&7) - (l>>3)) & 7 (rotation;
    // row group bases are multiples of 8 so the rotation amount is l>>3).
    const int srow   = lane >> 3;
    const int schunk = ((lane & 7) - srow) & 7;
    const unsigned char* aSrc = A + (size_t)(tile_m + wave * 8 + srow) * K_DIM + schunk * 16;
    const unsigned char* bSrc = B + (size_t)(tile_n + wave * 8 + srow) * K_DIM + schunk * 16;

    floatx4 acc[4][4];
    #pragma unroll
    for (int i = 0; i < 4; ++i)
        #pragma unroll
        for (int j = 0; j < 4; ++j)
            acc[i][j] = (floatx4){0.f, 0.f, 0.f, 0.f};

    const int wm = (wave >> 1) * 64;   // wave quadrant within 128x128
    const int wn = (wave & 1) * 64;

    // Frag read slots: lane (quad,m) wants k-bytes quad*32..+31 = chunks
    // 2q, 2q+1 of row m, stored at slots (chunk + m) & 7. m & 7 == l15 & 7
    // (wm, im*16 are multiples of 8), so slots are im-independent.
    const int s0 = (2 * quad + l15) & 7;
    const int s1 = (2 * quad + 1 + l15) & 7;

    for (int k0 = 0; k0 < K_DIM; k0 += BK) {
        #pragma unroll
        for (int r = 0; r < 4; ++r) {
            load_lds16(aSrc + (size_t)(r * 32) * K_DIM, (char*)sA + (r * 4 + wave) * 1024);
            load_lds16(bSrc + (size_t)(r * 32) * K_DIM, (char*)sB + (r * 4 + wave) * 1024);
        }
        __syncthreads();   // drains vmcnt -> tiles visible

        int8v a[4];
        #pragma unroll
        for (int im = 0; im < 4; ++im) {
            const unsigned char* p = sA + (wm + im * 16 + l15) * BK;
            ((int4v*)&a[im])[0] = *(const int4v*)(p + s0 * 16);
            ((int4v*)&a[im])[1] = *(const int4v*)(p + s1 * 16);
        }
        #pragma unroll
        for (int in = 0; in < 4; ++in) {
            const unsigned char* p = sB + (wn + in * 16 + l15) * BK;
            int8v b;
            ((int4v*)&b)[0] = *(const int4v*)(p + s0 * 16);
            ((int4v*)&b)[1] = *(const int4v*)(p + s1 * 16);
            #pragma unroll
            for (int im = 0; im < 4; ++im)
                acc[im][in] = __builtin_amdgcn_mfma_scale_f32_16x16x128_f8f6f4(
                    a[im], b, acc[im][in],
                    0 /*cbsz: A=e4m3*/, 0 /*blgp: B=e4m3*/,
                    0, 0x7F7F7F7F,   // scale_a opsel, E8M0 1.0 in every byte
                    0, 0x7F7F7F7F);  // scale_b
        }

        __syncthreads();   // all waves done reading before next overwrite
        aSrc += BK;
        bSrc += BK;
    }

    // Epilogue: dist^2 = nx[m] + nc[p] - 2*dot. Per-row min over this block's
    // 128 columns, then one atomicMin (positive-float uint bits) per row.
    // C/D layout is shape-determined, dtype-independent (guide m121-m128):
    // row = quad*4 + i, col = l15 within each 16x16 tile.
    float cn[4];
    #pragma unroll
    for (int in = 0; in < 4; ++in) cn[in] = nc[tile_n + wn + in * 16 + l15];

    #pragma unroll
    for (int im = 0; im < 4; ++im) {
        #pragma unroll
        for (int i = 0; i < 4; ++i) {
            float v =        cn[0] - 2.f * acc[im][0][i];
            v = fminf(v, cn[1] - 2.f * acc[im][1][i]);
            v = fminf(v, cn[2] - 2.f * acc[im][2][i]);
            v = fminf(v, cn[3] - 2.f * acc[im][3][i]);
            // min across the 16 lanes sharing this output row
            v = fminf(v, __shfl_xor(v, 8, 16));
            v = fminf(v, __shfl_xor(v, 4, 16));
            v = fminf(v, __shfl_xor(v, 2, 16));
            v = fminf(v, __shfl_xor(v, 1, 16));
            if (l15 == 0) {
                const int r = tile_m + wm + im * 16 + quad * 4 + i;
                atomicMin(&minbuf[r], __float_as_uint(v + nx[r]));
            }
        }
    }
}

__global__ void finalize_kernel(const unsigned int* __restrict__ minbuf,
                                float* __restrict__ out)
{
    const int i = blockIdx.x * 256 + threadIdx.x;
    if (i == 0) out[0] = 0.0f;                 // loss (eval mode)
    if (i < M_ROWS) out[1 + i] = sqrtf(__uint_as_float(minbuf[i]));
}

extern "C" void kernel_launch(void* const* d_in, const int* in_sizes, int n_in,
                              void* d_out, int out_size, void* d_ws, size_t ws_size,
                              hipStream_t stream)
{
    const float* embeds = (const float*)d_in[0];   // [8, 3136, 1536] fp32
    const float* cents  = (const float*)d_in[1];   // [4096, 1536] fp32
    float* out = (float*)d_out;                    // [1 + 25088] fp32

    char* ws = (char*)d_ws;
    const size_t offA   = 0;                                   // 38,535,168 B (fp8)
    const size_t offB   = offA + (size_t)M_ROWS * K_DIM;       //  6,291,456 B (fp8)
    const size_t offNx  = offB + (size_t)N_CENT * K_DIM;       //    100,352 B
    const size_t offNc  = offNx + (size_t)M_ROWS * 4;          //     16,384 B
    const size_t offMin = offNc + (size_t)N_CENT * 4;          //    100,352 B

    unsigned char* A8 = (unsigned char*)(ws + offA);
    unsigned char* B8 = (unsigned char*)(ws + offB);
    float* nx = (float*)(ws + offNx);
    float* nc = (float*)(ws + offNc);
    unsigned int* minbuf = (unsigned int*)(ws + offMin);

    convert_rows<<<M_ROWS / 4, 256, 0, stream>>>(embeds, (unsigned int*)A8, nx, minbuf, M_ROWS);
    convert_rows<<<N_CENT / 4, 256, 0, stream>>>(cents, (unsigned int*)B8, nc, nullptr, N_CENT);

    dim3 grid(N_CENT / TILE, M_ROWS / TILE);   // x = column tiles (fast) for A-tile L2/LLC reuse
    gemm_min<<<grid, 256, 0, stream>>>(A8, B8, nx, nc, minbuf);

    finalize_kernel<<<(M_ROWS + 255) / 256, 256, 0, stream>>>(minbuf, out);
}